// Round 5
// baseline (1423.333 us; speedup 1.0000x reference)
//
#include <hip/hip_runtime.h>
#include <hip/hip_bf16.h>
#include <stdint.h>

// ---------------- problem constants ----------------
#define M_DIM 8192            // B*S = 4*2048
#define N_DIM 11008
#define K_DIM 4096
#define NTILE 64              // K-tiles of 64: K/64

typedef unsigned short ushort_t;
typedef __attribute__((ext_vector_type(8))) short  short8;
typedef __attribute__((ext_vector_type(8))) __bf16 bf16x8;
typedef __attribute__((ext_vector_type(4))) float  f32x4;

__device__ __forceinline__ ushort_t f2bf(float f){
  uint32_t u = __builtin_bit_cast(uint32_t, f);
  u += 0x7FFFu + ((u >> 16) & 1u);
  return (ushort_t)(u >> 16);
}

__device__ __forceinline__ void gll16(const void* g, void* l){
  __builtin_amdgcn_global_load_lds(
      (const __attribute__((address_space(1))) void*)g,
      (__attribute__((address_space(3))) void*)l,
      16, 0, 0);
}

// ---------------- pre-pass converts ----------------
__global__ void cvt_x_kernel(const float* __restrict__ x, ushort_t* __restrict__ xb){
  const int TOT = 33554432/8;
  for (int c = blockIdx.x*blockDim.x + threadIdx.x; c < TOT; c += gridDim.x*blockDim.x){
    size_t i = (size_t)c*8;
    float4 v0 = *(const float4*)(x+i);
    float4 v1 = *(const float4*)(x+i+4);
    short8 o;
    o[0]=(short)f2bf(v0.x); o[1]=(short)f2bf(v0.y); o[2]=(short)f2bf(v0.z); o[3]=(short)f2bf(v0.w);
    o[4]=(short)f2bf(v1.x); o[5]=(short)f2bf(v1.y); o[6]=(short)f2bf(v1.z); o[7]=(short)f2bf(v1.w);
    *(short8*)(xb+i) = o;
  }
}

__global__ void cvt_w_kernel(const int* __restrict__ q, const float* __restrict__ scale,
                             const float* __restrict__ zp, ushort_t* __restrict__ wb){
  const int TOT = 45088768/8;
  for (int c = blockIdx.x*blockDim.x + threadIdx.x; c < TOT; c += gridDim.x*blockDim.x){
    int row = c >> 9;
    float s = scale[row];
    float b = -zp[row]*s;
    size_t i = (size_t)c*8;
    int4 q0 = *(const int4*)(q+i);
    int4 q1 = *(const int4*)(q+i+4);
    short8 o;
    o[0]=(short)f2bf((float)q0.x*s+b); o[1]=(short)f2bf((float)q0.y*s+b);
    o[2]=(short)f2bf((float)q0.z*s+b); o[3]=(short)f2bf((float)q0.w*s+b);
    o[4]=(short)f2bf((float)q1.x*s+b); o[5]=(short)f2bf((float)q1.y*s+b);
    o[6]=(short)f2bf((float)q1.z*s+b); o[7]=(short)f2bf((float)q1.w*s+b);
    *(short8*)(wb+i) = o;
  }
}

// ============== 256x256 8-phase GEMM, register-pipelined (r5) ==============
// Same schedule as r4 (LDs for phase p+1 overlap MFMA of phase p in each
// barrier-bounded window) with TWO correctness hardenings:
//  (1) peeled tail iteration with vmcnt(0) at ph4 — r3/r4's counted vmcnt(4)
//      under-retires in the last iteration (t2/t3 stages skipped => only 8
//      outstanding, so buf1.h1 stages were NOT published before their reads:
//      the r4 absmax-33 race, latent in r3).
//  (2) sched_barrier(0) pinned around the counted vmcnt sites — the
//      retirement proof depends on gll16-vs-vmcnt issue order.
// Steady-state proof (j=0..30) unchanged from r3/r4:
//  ph4 vmcnt(4) retires {prev ph7, prev ph8, ph1, ph2} = all of buf1;
//  ph8 vmcnt(4) retires {ph3..ph6} = all of buf0(t2).
// WAR: every ds_read completes before the MFMA one phase later (in-order DS
// return, lgkm wait before MFMA), hence >=1 barrier before the earliest
// conflicting stage (checked per phase for all 8 stages).

#define BAR() do{ asm volatile("" ::: "memory"); \
  __builtin_amdgcn_s_barrier(); \
  asm volatile("" ::: "memory"); }while(0)

#define VMCNT4() do{ __builtin_amdgcn_sched_barrier(0); \
  asm volatile("s_waitcnt vmcnt(4)" ::: "memory"); \
  __builtin_amdgcn_sched_barrier(0); }while(0)

#define VMCNT0() do{ __builtin_amdgcn_sched_barrier(0); \
  asm volatile("s_waitcnt vmcnt(0)" ::: "memory"); \
  __builtin_amdgcn_sched_barrier(0); }while(0)

#define LDA_TO(DST, BUF, G) do{ \
  const ushort_t* _b = &As[BUF][wm][((G)*64 + rl)*64]; \
  _Pragma("unroll") for (int mf=0; mf<4; ++mf){ \
    DST[mf][0] = *(const bf16x8*)(_b + mf*1024 + offk0); \
    DST[mf][1] = *(const bf16x8*)(_b + mf*1024 + offk1); } \
}while(0)

#define LDB_TO(DST, BUF, NG) do{ \
  const ushort_t* _b = &Bs[BUF][hb][(hbr + (NG)*32 + rl)*64]; \
  _Pragma("unroll") for (int nfl=0; nfl<2; ++nfl){ \
    DST[nfl][0] = *(const bf16x8*)(_b + nfl*1024 + offk0); \
    DST[nfl][1] = *(const bf16x8*)(_b + nfl*1024 + offk1); } \
}while(0)

#define MFMA_Q(AF, BF, MG, NG) do{ \
  __builtin_amdgcn_s_setprio(1); \
  _Pragma("unroll") for (int mf=0; mf<4; ++mf) \
    _Pragma("unroll") for (int nfl=0; nfl<2; ++nfl) \
      _Pragma("unroll") for (int kk=0; kk<2; ++kk) \
        acc[(MG)*4+mf][(NG)*2+nfl] = __builtin_amdgcn_mfma_f32_16x16x32_bf16( \
            AF[mf][kk], BF[nfl][kk], acc[(MG)*4+mf][(NG)*2+nfl], 0,0,0); \
  __builtin_amdgcn_s_setprio(0); \
}while(0)

#define STAGE_A(BUF, H, T) do{ \
  gll16(aS[H][0] + (size_t)(T)*64, &As[BUF][H][w*1024]); \
  gll16(aS[H][1] + (size_t)(T)*64, &As[BUF][H][w*1024+512]); }while(0)

#define STAGE_B(BUF, H, T) do{ \
  gll16(bS[H][0] + (size_t)(T)*64, &Bs[BUF][H][w*1024]); \
  gll16(bS[H][1] + (size_t)(T)*64, &Bs[BUF][H][w*1024+512]); }while(0)

__global__ __launch_bounds__(512, 2)
void qgemm256(const ushort_t* __restrict__ Xb, const ushort_t* __restrict__ Wb,
              const float* __restrict__ g_bias, float* __restrict__ Y)
{
  __shared__ __align__(16) ushort_t As[2][2][8192];   // 64 KB
  __shared__ __align__(16) ushort_t Bs[2][2][8192];   // 64 KB

  const int t    = threadIdx.x;
  const int lane = t & 63;
  const int w    = t >> 6;        // 0..7
  const int wm   = w >> 2;        // 0..1  (M half)
  const int wn   = w & 3;         // 0..3  (N quarter)
  const int hb   = wn >> 1;       // B half
  const int hbr  = (wn & 1) * 64; // row base within B half

  const int GM2 = M_DIM/256, GN2 = N_DIM/256;   // 32, 43
  const int NWG2 = GM2*GN2;                      // 1376 (%8==0)
  int bid = blockIdx.x;
  int swz = (bid & 7) * (NWG2/8) + (bid >> 3);
  int by = swz / GN2, bx = swz - by*GN2;
  const int brow = by*256, bcol = bx*256;

  const int rl    = lane & 15;
  const int offk0 = (((lane>>4)    ) ^ (lane&7)) * 8;   // kk=0 (elements)
  const int offk1 = (((lane>>4) + 4) ^ (lane&7)) * 8;   // kk=1

  // staging geometry: wave w owns rows 16w..16w+15 of each half-tile;
  // lane fetches pre-swizzled global slot so LDS lands XOR-swizzled.
  const int g_r = lane >> 3;
  const int g_s = (lane & 7) ^ g_r;
  const ushort_t* aS[2][2];
  const ushort_t* bS[2][2];
  #pragma unroll
  for (int h=0; h<2; ++h)
    #pragma unroll
    for (int ci=0; ci<2; ++ci){
      int r8 = 8*(2*w+ci) + g_r;
      aS[h][ci] = Xb + (size_t)(brow + h*128 + r8)*K_DIM + g_s*8;
      bS[h][ci] = Wb + (size_t)(bcol + h*128 + r8)*K_DIM + g_s*8;
    }

  f32x4 acc[8][4] = {};
  bf16x8 afX[4][2], afY[4][2];   // A fragments: G0 / G1
  bf16x8 bfX[2][2], bfY[2][2];   // B fragments: N01 / N23

  // ---- prologue: buf0 <- tile0 (4 halves), buf1 <- tile1 (B.h0, A.h0) ----
  STAGE_B(0,0,0); STAGE_A(0,0,0); STAGE_A(0,1,0); STAGE_B(0,1,0);
  STAGE_B(1,0,1); STAGE_A(1,0,1);
  VMCNT4();                 // retire the 4 buf0 stages; buf1 h0s stay in flight
  BAR();
  LDA_TO(afX, 0, 0);        // operands for ph1's MFMA
  LDB_TO(bfX, 0, 0);

  #pragma unroll 1
  for (int j=0; j<NTILE/2-1; ++j){      // j=0..30: full stages, counted vmcnt
    const int t1 = 2*j+1, t2 = 2*j+2, t3 = 2*j+3;
    // ph1: MFMA Q(0,0) buf0 | LD bfN23(buf0) for ph2
    STAGE_A(1,1,t1);
    BAR();
    LDB_TO(bfY, 0, 1);
    MFMA_Q(afX, bfX, 0, 0);
    BAR();
    // ph2: MFMA Q(0,1) | LD afG1(buf0) for ph3
    STAGE_B(1,1,t1);
    BAR();
    LDA_TO(afY, 0, 1);
    MFMA_Q(afX, bfY, 0, 1);
    BAR();
    // ph3: MFMA Q(1,0)
    STAGE_B(0,0,t2);
    BAR();
    MFMA_Q(afY, bfX, 1, 0);
    BAR();
    // ph4: vmcnt publishes buf1 -> LD afG0,bfN01(buf1) | MFMA Q(1,1)
    STAGE_A(0,0,t2);
    VMCNT4();
    BAR();
    LDA_TO(afX, 1, 0);
    LDB_TO(bfX, 1, 0);
    MFMA_Q(afY, bfY, 1, 1);
    BAR();
    // ph5: MFMA Q(0,0) buf1 | LD bfN23(buf1)
    STAGE_A(0,1,t2);
    BAR();
    LDB_TO(bfY, 1, 1);
    MFMA_Q(afX, bfX, 0, 0);
    BAR();
    // ph6: MFMA Q(0,1) | LD afG1(buf1)
    STAGE_B(0,1,t2);
    BAR();
    LDA_TO(afY, 1, 1);
    MFMA_Q(afX, bfY, 0, 1);
    BAR();
    // ph7: MFMA Q(1,0)
    STAGE_B(1,0,t3);
    BAR();
    MFMA_Q(afY, bfX, 1, 0);
    BAR();
    // ph8: vmcnt publishes buf0(t2) -> LD afG0,bfN01(buf0) | MFMA Q(1,1)
    STAGE_A(1,0,t3);
    VMCNT4();
    BAR();
    LDA_TO(afX, 0, 0);
    LDB_TO(bfX, 0, 0);
    MFMA_Q(afY, bfY, 1, 1);
    BAR();
  }

  // ---- peeled tail (tiles 62,63): no t2/t3 stages exist, so the counted
  // vmcnt(4) would under-retire (the r4 race). Full drain at ph4 publishes
  // ALL of buf1 (incl. the ph1/ph2 stages of t1=63) before its reads.
  {
    const int t1 = NTILE-1;   // 63
    // ph1
    STAGE_A(1,1,t1);
    BAR();
    LDB_TO(bfY, 0, 1);
    MFMA_Q(afX, bfX, 0, 0);
    BAR();
    // ph2
    STAGE_B(1,1,t1);
    BAR();
    LDA_TO(afY, 0, 1);
    MFMA_Q(afX, bfY, 0, 1);
    BAR();
    // ph3
    BAR();
    MFMA_Q(afY, bfX, 1, 0);
    BAR();
    // ph4: FULL drain -> buf1 (tile 63) fully published
    VMCNT0();
    BAR();
    LDA_TO(afX, 1, 0);
    LDB_TO(bfX, 1, 0);
    MFMA_Q(afY, bfY, 1, 1);
    BAR();
    // ph5
    BAR();
    LDB_TO(bfY, 1, 1);
    MFMA_Q(afX, bfX, 0, 0);
    BAR();
    // ph6
    BAR();
    LDA_TO(afY, 1, 1);
    MFMA_Q(afX, bfY, 0, 1);
    BAR();
    // ph7
    BAR();
    MFMA_Q(afY, bfX, 1, 0);
    BAR();
    // ph8
    BAR();
    MFMA_Q(afY, bfY, 1, 1);
    BAR();
  }

  // ---- epilogue: C/D layout col=lane&15, row=(lane>>4)*4+i ----
  const int cl = lane & 15;
  const int rq = (lane >> 4) << 2;
  #pragma unroll
  for (int nf=0; nf<4; ++nf){
    int col = bcol + wn*64 + nf*16 + cl;
    float bvs = g_bias[col];
    #pragma unroll
    for (int mf=0; mf<8; ++mf){
      int row = brow + wm*128 + mf*16 + rq;
      f32x4 v = acc[mf][nf];
      #pragma unroll
      for (int i=0;i<4;++i)
        Y[(size_t)(row+i)*N_DIM + col] = v[i] + bvs;
    }
  }
}

// ============== fallback 128x128 dbuf GEMM (paths B/C, proven r2) ==============
template<bool PRE_A, bool PRE_B>
__global__ __launch_bounds__(256, 2)
void qgemm(const ushort_t* __restrict__ Xb, const float* __restrict__ Xf,
           const ushort_t* __restrict__ Wb, const int* __restrict__ Wq,
           const float* __restrict__ g_scale, const float* __restrict__ g_zp,
           const float* __restrict__ g_bias, float* __restrict__ Y)
{
  const int BM=128, BK=64, NT=K_DIM/BK, GRID_N=N_DIM/128, NWG=(M_DIM/128)*GRID_N;
  __shared__ __align__(16) ushort_t As[2][BM*BK];
  __shared__ __align__(16) ushort_t Bs[2][BM*BK];

  const int t = threadIdx.x, lane = t & 63, w = t >> 6;
  const int wr = w >> 1, wc = w & 1;
  int bid = blockIdx.x;
  int swz = (bid & 7) * (NWG/8) + (bid >> 3);
  int by = swz / GRID_N, bx = swz - by*GRID_N;
  const int brow = by*128, bcol = bx*128;

  f32x4 acc[4][4] = {};
  const int s8 = t & 7, r0 = t >> 3;
  const int g_r = lane >> 3, g_s = (lane & 7) ^ g_r;

  float wsc[4], wof[4];
  if constexpr (!PRE_B){
    #pragma unroll
    for (int i=0;i<4;++i){
      int n = bcol + r0 + 32*i;
      float sc = g_scale[n];
      wsc[i] = sc; wof[i] = -g_zp[n]*sc;
    }
  }
  float4 ax[4][2]; int4 bq[4][2];
  auto loadA = [&](int kt){
    #pragma unroll
    for (int i=0;i<4;++i){
      const float* p = Xf + (size_t)(brow + r0 + 32*i)*K_DIM + kt*BK + s8*8;
      ax[i][0] = *(const float4*)p; ax[i][1] = *(const float4*)(p+4);
    }};
  auto loadB = [&](int kt){
    #pragma unroll
    for (int i=0;i<4;++i){
      const int* p = Wq + (size_t)(bcol + r0 + 32*i)*K_DIM + kt*BK + s8*8;
      bq[i][0] = *(const int4*)p; bq[i][1] = *(const int4*)(p+4);
    }};
  auto stageA_gll = [&](int buf, int kt){
    #pragma unroll
    for (int i=0;i<4;++i){ int c = w*4 + i;
      gll16(Xb + (size_t)(brow + 8*c + g_r)*K_DIM + kt*BK + g_s*8, &As[buf][c*512]); }};
  auto stageB_gll = [&](int buf, int kt){
    #pragma unroll
    for (int i=0;i<4;++i){ int c = w*4 + i;
      gll16(Wb + (size_t)(bcol + 8*c + g_r)*K_DIM + kt*BK + g_s*8, &Bs[buf][c*512]); }};
  auto stageA_reg = [&](int buf){
    #pragma unroll
    for (int i=0;i<4;++i){
      short8 o;
      o[0]=(short)f2bf(ax[i][0].x); o[1]=(short)f2bf(ax[i][0].y);
      o[2]=(short)f2bf(ax[i][0].z); o[3]=(short)f2bf(ax[i][0].w);
      o[4]=(short)f2bf(ax[i][1].x); o[5]=(short)f2bf(ax[i][1].y);
      o[6]=(short)f2bf(ax[i][1].z); o[7]=(short)f2bf(ax[i][1].w);
      int r = r0 + 32*i; int idx = (r*BK + s8*8) ^ ((r&7)<<3);
      *(short8*)&As[buf][idx] = o; }};
  auto stageB_reg = [&](int buf){
    #pragma unroll
    for (int i=0;i<4;++i){
      short8 o;
      o[0]=(short)f2bf((float)bq[i][0].x*wsc[i]+wof[i]);
      o[1]=(short)f2bf((float)bq[i][0].y*wsc[i]+wof[i]);
      o[2]=(short)f2bf((float)bq[i][0].z*wsc[i]+wof[i]);
      o[3]=(short)f2bf((float)bq[i][0].w*wsc[i]+wof[i]);
      o[4]=(short)f2bf((float)bq[i][1].x*wsc[i]+wof[i]);
      o[5]=(short)f2bf((float)bq[i][1].y*wsc[i]+wof[i]);
      o[6]=(short)f2bf((float)bq[i][1].z*wsc[i]+wof[i]);
      o[7]=(short)f2bf((float)bq[i][1].w*wsc[i]+wof[i]);
      int r = r0 + 32*i; int idx = (r*BK + s8*8) ^ ((r&7)<<3);
      *(short8*)&Bs[buf][idx] = o; }};

  if constexpr (!PRE_A) loadA(0);
  if constexpr (!PRE_B) loadB(0);
  if constexpr (PRE_A) stageA_gll(0,0); else stageA_reg(0);
  if constexpr (PRE_B) stageB_gll(0,0); else stageB_reg(0);
  if constexpr (!PRE_A) { if (NT > 1) loadA(1); }
  if constexpr (!PRE_B) { if (NT > 1) loadB(1); }

  int cur = 0;
  for (int kt=0; kt<NT; ++kt){
    asm volatile("s_waitcnt vmcnt(0) lgkmcnt(0)" ::: "memory");
    __builtin_amdgcn_sched_barrier(0);
    __syncthreads();
    const int nxt = cur ^ 1;
    if (kt+1 < NT){
      if constexpr (PRE_A) stageA_gll(nxt, kt+1); else stageA_reg(nxt);
      if constexpr (PRE_B) stageB_gll(nxt, kt+1); else stageB_reg(nxt);
      if constexpr (!PRE_A) { if (kt+2 < NT) loadA(kt+2); }
      if constexpr (!PRE_B) { if (kt+2 < NT) loadB(kt+2); }
    }
    const ushort_t* as = As[cur];
    const ushort_t* bs = Bs[cur];
    #pragma unroll
    for (int kk=0; kk<2; ++kk){
      bf16x8 af[4], bfr[4];
      const int klo = kk*32 + ((lane>>4)<<3);
      #pragma unroll
      for (int mf=0; mf<4; ++mf){
        int r = wr*64 + mf*16 + (lane&15);
        af[mf] = *(const bf16x8*)&as[(r*BK + klo) ^ ((r&7)<<3)];
      }
      #pragma unroll
      for (int nf=0; nf<4; ++nf){
        int r = wc*64 + nf*16 + (lane&15);
        bfr[nf] = *(const bf16x8*)&bs[(r*BK + klo) ^ ((r&7)<<3)];
      }
      #pragma unroll
      for (int mf=0; mf<4; ++mf)
        #pragma unroll
        for (int nf=0; nf<4; ++nf)
          acc[mf][nf] = __builtin_amdgcn_mfma_f32_16x16x32_bf16(af[mf], bfr[nf], acc[mf][nf], 0,0,0);
    }
    cur = nxt;
  }
  const int cl = lane & 15, rq = (lane >> 4) << 2;
  #pragma unroll
  for (int nf=0; nf<4; ++nf){
    int col = bcol + wc*64 + nf*16 + cl;
    float bvs = g_bias[col];
    #pragma unroll
    for (int mf=0; mf<4; ++mf){
      int row = brow + wr*64 + mf*16 + rq;
      f32x4 v = acc[mf][nf];
      #pragma unroll
      for (int i=0;i<4;++i)
        Y[(size_t)(row+i)*N_DIM + col] = v[i] + bvs;
    }
  }
}

// ---------------- launch ----------------
extern "C" void kernel_launch(void* const* d_in, const int* in_sizes, int n_in,
                              void* d_out, int out_size, void* d_ws, size_t ws_size,
                              hipStream_t stream) {
  const float* x     = (const float*)d_in[0];
  const int*   qw    = (const int*)  d_in[1];
  const float* scale = (const float*)d_in[2];
  const float* zp    = (const float*)d_in[3];
  const float* bias  = (const float*)d_in[4];
  float* y = (float*)d_out;

  const size_t XB = (size_t)M_DIM*K_DIM*2;
  const size_t WB = (size_t)N_DIM*K_DIM*2;

  if (ws_size >= XB + WB){
    ushort_t* xb = (ushort_t*)d_ws;
    ushort_t* wb = (ushort_t*)((char*)d_ws + XB);
    cvt_x_kernel<<<2048, 256, 0, stream>>>(x, xb);
    cvt_w_kernel<<<2048, 256, 0, stream>>>(qw, scale, zp, wb);
    qgemm256<<<dim3((M_DIM/256)*(N_DIM/256)), dim3(512), 0, stream>>>(xb, wb, bias, y);
  } else if (ws_size >= WB){
    ushort_t* wb = (ushort_t*)d_ws;
    cvt_w_kernel<<<2048, 256, 0, stream>>>(qw, scale, zp, wb);
    qgemm<false,true><<<dim3((M_DIM/128)*(N_DIM/128)), dim3(256), 0, stream>>>(nullptr, x, wb, nullptr, scale, zp, bias, y);
  } else {
    qgemm<false,false><<<dim3((M_DIM/128)*(N_DIM/128)), dim3(256), 0, stream>>>(nullptr, x, nullptr, qw, scale, zp, bias, y);
  }
}

// Round 6
// 938.770 us; speedup vs baseline: 1.5162x; 1.5162x over previous
//
#include <hip/hip_runtime.h>
#include <hip/hip_bf16.h>
#include <stdint.h>

// ---------------- problem constants ----------------
#define M_DIM 8192            // B*S = 4*2048
#define N_DIM 11008
#define K_DIM 4096
#define NTILE 64              // K-tiles of 64

typedef unsigned short ushort_t;
typedef __attribute__((ext_vector_type(8)))  short  short8;
typedef __attribute__((ext_vector_type(8)))  __bf16 bf16x8;
typedef __attribute__((ext_vector_type(4)))  float  f32x4;
typedef __attribute__((ext_vector_type(16))) float  f32x16;

__device__ __forceinline__ ushort_t f2bf(float f){
  uint32_t u = __builtin_bit_cast(uint32_t, f);
  u += 0x7FFFu + ((u >> 16) & 1u);
  return (ushort_t)(u >> 16);
}

__device__ __forceinline__ void gll16(const void* g, void* l){
  __builtin_amdgcn_global_load_lds(
      (const __attribute__((address_space(1))) void*)g,
      (__attribute__((address_space(3))) void*)l,
      16, 0, 0);
}

// ---------------- pre-pass converts ----------------
__global__ void cvt_x_kernel(const float* __restrict__ x, ushort_t* __restrict__ xb){
  const int TOT = 33554432/8;
  for (int c = blockIdx.x*blockDim.x + threadIdx.x; c < TOT; c += gridDim.x*blockDim.x){
    size_t i = (size_t)c*8;
    float4 v0 = *(const float4*)(x+i);
    float4 v1 = *(const float4*)(x+i+4);
    short8 o;
    o[0]=(short)f2bf(v0.x); o[1]=(short)f2bf(v0.y); o[2]=(short)f2bf(v0.z); o[3]=(short)f2bf(v0.w);
    o[4]=(short)f2bf(v1.x); o[5]=(short)f2bf(v1.y); o[6]=(short)f2bf(v1.z); o[7]=(short)f2bf(v1.w);
    *(short8*)(xb+i) = o;
  }
}

__global__ void cvt_w_kernel(const int* __restrict__ q, const float* __restrict__ scale,
                             const float* __restrict__ zp, ushort_t* __restrict__ wb){
  const int TOT = 45088768/8;
  for (int c = blockIdx.x*blockDim.x + threadIdx.x; c < TOT; c += gridDim.x*blockDim.x){
    int row = c >> 9;
    float s = scale[row];
    float b = -zp[row]*s;
    size_t i = (size_t)c*8;
    int4 q0 = *(const int4*)(q+i);
    int4 q1 = *(const int4*)(q+i+4);
    short8 o;
    o[0]=(short)f2bf((float)q0.x*s+b); o[1]=(short)f2bf((float)q0.y*s+b);
    o[2]=(short)f2bf((float)q0.z*s+b); o[3]=(short)f2bf((float)q0.w*s+b);
    o[4]=(short)f2bf((float)q1.x*s+b); o[5]=(short)f2bf((float)q1.y*s+b);
    o[6]=(short)f2bf((float)q1.z*s+b); o[7]=(short)f2bf((float)q1.w*s+b);
    *(short8*)(wb+i) = o;
  }
}

// ====== 256x256 GEMM, 32x32x16 MFMA, slice-pipelined, 1 barrier/K-tile ======
// 8 waves (2M x 4N), per-wave 128x64 out = 4x2 frags of 32x32.
// acc: 8 x f32x16 (128 regs). Slices double-buffered in regs (2 x 24 regs):
// per kstep(K=16): 6 ds_read_b128 for kstep+1 overlap 8 MFMA of kstep (WAR
// on the alternating slice regs throttles hoisting to exactly 1 ahead).
// Sync per K-tile: stages (8 gll16) issued at tile start -> full K-tile of
// compute (~2500cyc) -> s_waitcnt vmcnt(0) lgkmcnt(0) -> s_barrier.
//   WAR: lgkmcnt(0) before BAR => all waves' reads of buf done before any
//        wave's post-BAR stage of that buf.
//   RAW: vmcnt(0) before BAR => staged buf published before any read of it.
// Tail tile needs no special case (stage simply absent).

#define BAR() do{ asm volatile("" ::: "memory"); \
  __builtin_amdgcn_s_barrier(); \
  asm volatile("" ::: "memory"); }while(0)

#define DRAIN() asm volatile("s_waitcnt vmcnt(0) lgkmcnt(0)" ::: "memory")

// load slice for kstep KS from buffer CUR into (SLA[4], SLB[2])
#define LOADSL(SLA, SLB, CUR, KS) do{ \
  const int _s = (((2*(KS)) + kx) ^ l7) * 8; \
  const ushort_t* _a = &As[CUR][aRow*64 + _s]; \
  SLA[0] = *(const bf16x8*)(_a); \
  SLA[1] = *(const bf16x8*)(_a + 2048); \
  SLA[2] = *(const bf16x8*)(_a + 4096); \
  SLA[3] = *(const bf16x8*)(_a + 6144); \
  const ushort_t* _bp = &Bs[CUR][bRow*64 + _s]; \
  SLB[0] = *(const bf16x8*)(_bp); \
  SLB[1] = *(const bf16x8*)(_bp + 2048); \
}while(0)

#define MM(SLA, SLB) do{ \
  __builtin_amdgcn_s_setprio(1); \
  _Pragma("unroll") for (int mf=0; mf<4; ++mf) \
    _Pragma("unroll") for (int nf=0; nf<2; ++nf) \
      acc[mf][nf] = __builtin_amdgcn_mfma_f32_32x32x16_bf16( \
          SLA[mf], SLB[nf], acc[mf][nf], 0, 0, 0); \
  __builtin_amdgcn_s_setprio(0); \
}while(0)

#define STAGE(CUR, T) do{ \
  _Pragma("unroll") for (int c=0;c<4;++c) \
    gll16(aSrc[c] + (size_t)(T)*64, &As[CUR][(4*w+c)*512]); \
  _Pragma("unroll") for (int c=0;c<4;++c) \
    gll16(bSrc[c] + (size_t)(T)*64, &Bs[CUR][(4*w+c)*512]); \
}while(0)

__global__ __launch_bounds__(512, 2)
void qgemm256(const ushort_t* __restrict__ Xb, const ushort_t* __restrict__ Wb,
              const float* __restrict__ g_bias, float* __restrict__ Y)
{
  __shared__ __align__(16) ushort_t As[2][16384];   // 2 x 32 KB
  __shared__ __align__(16) ushort_t Bs[2][16384];   // 2 x 32 KB

  const int t    = threadIdx.x;
  const int lane = t & 63;
  const int w    = __builtin_amdgcn_readfirstlane(t >> 6);  // 0..7, wave-uniform
  const int wm   = w >> 2;        // 0..1  (M half: 128 rows)
  const int wn   = w & 3;         // 0..3  (N quarter: 64 cols)

  const int GM2 = M_DIM/256, GN2 = N_DIM/256;    // 32, 43
  const int NWG2 = GM2*GN2;                      // 1376 (%8==0)
  int bid = blockIdx.x;
  int swz = (bid & 7) * (NWG2/8) + (bid >> 3);
  int by = swz / GN2, bx = swz - by*GN2;
  const int brow = by*256, bcol = bx*256;

  // lane constants
  const int rl31 = lane & 31;
  const int kx   = lane >> 5;           // k-half selector (0/1)
  const int l7   = lane & 7;
  const int aRow = wm*128 + rl31;       // A LDS row base (+ mf*32 via imm)
  const int bRow = wn*64  + rl31;       // B LDS row base (+ nf*32 via imm)

  // staging source pointers (pre-swizzled global slot => LDS lands swizzled:
  // LDS[row][s] = G[row][s ^ (row&7)], read applies same XOR -> identity)
  const int g_r = lane >> 3;            // row within 8-row chunk (= row&7)
  const int g_s = (lane & 7) ^ g_r;     // pre-swizzled 16B slot
  const ushort_t* aSrc[4];
  const ushort_t* bSrc[4];
  #pragma unroll
  for (int c=0;c<4;++c){
    int r8 = 8*(4*w+c) + g_r;
    aSrc[c] = Xb + (size_t)(brow + r8)*K_DIM + g_s*8;
    bSrc[c] = Wb + (size_t)(bcol + r8)*K_DIM + g_s*8;
  }

  f32x16 acc[4][2] = {};
  bf16x8 aX[4], aY[4];
  bf16x8 bX[2], bY[2];

  // ---- prologue ----
  STAGE(0, 0);
  DRAIN();
  BAR();
  LOADSL(aX, bX, 0, 0);

  #pragma unroll 1
  for (int kt=0; kt<NTILE-1; ++kt){
    const int cur = kt & 1;
    STAGE(cur^1, kt+1);                 // DMA flies under this tile's compute
    LOADSL(aY, bY, cur, 1);  MM(aX, bX);
    LOADSL(aX, bX, cur, 2);  MM(aY, bY);
    LOADSL(aY, bY, cur, 3);  MM(aX, bX);
    DRAIN();                            // reads done (WAR) + stages published (RAW)
    BAR();
    LOADSL(aX, bX, cur^1, 0);           // next tile ks0: overlaps ks3's MFMA
    MM(aY, bY);
  }
  // ---- tail tile (kt = 63, cur = 1): no staging, no trailing prefetch ----
  LOADSL(aY, bY, 1, 1);  MM(aX, bX);
  LOADSL(aX, bX, 1, 2);  MM(aY, bY);
  LOADSL(aY, bY, 1, 3);  MM(aX, bX);
  MM(aY, bY);

  // ---- epilogue: 32x32 C/D layout col=lane&31, row=(r&3)+8*(r>>2)+4*kx ----
  #pragma unroll
  for (int nf=0; nf<2; ++nf){
    const int col = bcol + wn*64 + nf*32 + rl31;
    const float bvs = g_bias[col];
    #pragma unroll
    for (int mf=0; mf<4; ++mf){
      const int rbase = brow + wm*128 + mf*32 + 4*kx;
      #pragma unroll
      for (int r=0; r<16; ++r){
        int row = rbase + (r&3) + 8*(r>>2);
        Y[(size_t)row*N_DIM + col] = acc[mf][nf][r] + bvs;
      }
    }
  }
}

// ============== fallback 128x128 dbuf GEMM (paths B/C, proven r2) ==============
template<bool PRE_A, bool PRE_B>
__global__ __launch_bounds__(256, 2)
void qgemm(const ushort_t* __restrict__ Xb, const float* __restrict__ Xf,
           const ushort_t* __restrict__ Wb, const int* __restrict__ Wq,
           const float* __restrict__ g_scale, const float* __restrict__ g_zp,
           const float* __restrict__ g_bias, float* __restrict__ Y)
{
  const int BM=128, BK=64, NT=K_DIM/BK, GRID_N=N_DIM/128, NWG=(M_DIM/128)*GRID_N;
  __shared__ __align__(16) ushort_t As[2][BM*BK];
  __shared__ __align__(16) ushort_t Bs[2][BM*BK];

  const int t = threadIdx.x, lane = t & 63, w = t >> 6;
  const int wr = w >> 1, wc = w & 1;
  int bid = blockIdx.x;
  int swz = (bid & 7) * (NWG/8) + (bid >> 3);
  int by = swz / GRID_N, bx = swz - by*GRID_N;
  const int brow = by*128, bcol = bx*128;

  f32x4 acc[4][4] = {};
  const int s8 = t & 7, r0 = t >> 3;
  const int g_r = lane >> 3, g_s = (lane & 7) ^ g_r;

  float wsc[4], wof[4];
  if constexpr (!PRE_B){
    #pragma unroll
    for (int i=0;i<4;++i){
      int n = bcol + r0 + 32*i;
      float sc = g_scale[n];
      wsc[i] = sc; wof[i] = -g_zp[n]*sc;
    }
  }
  float4 ax[4][2]; int4 bq[4][2];
  auto loadA = [&](int kt){
    #pragma unroll
    for (int i=0;i<4;++i){
      const float* p = Xf + (size_t)(brow + r0 + 32*i)*K_DIM + kt*BK + s8*8;
      ax[i][0] = *(const float4*)p; ax[i][1] = *(const float4*)(p+4);
    }};
  auto loadB = [&](int kt){
    #pragma unroll
    for (int i=0;i<4;++i){
      const int* p = Wq + (size_t)(bcol + r0 + 32*i)*K_DIM + kt*BK + s8*8;
      bq[i][0] = *(const int4*)p; bq[i][1] = *(const int4*)(p+4);
    }};
  auto stageA_gll = [&](int buf, int kt){
    #pragma unroll
    for (int i=0;i<4;++i){ int c = w*4 + i;
      gll16(Xb + (size_t)(brow + 8*c + g_r)*K_DIM + kt*BK + g_s*8, &As[buf][c*512]); }};
  auto stageB_gll = [&](int buf, int kt){
    #pragma unroll
    for (int i=0;i<4;++i){ int c = w*4 + i;
      gll16(Wb + (size_t)(bcol + 8*c + g_r)*K_DIM + kt*BK + g_s*8, &Bs[buf][c*512]); }};
  auto stageA_reg = [&](int buf){
    #pragma unroll
    for (int i=0;i<4;++i){
      short8 o;
      o[0]=(short)f2bf(ax[i][0].x); o[1]=(short)f2bf(ax[i][0].y);
      o[2]=(short)f2bf(ax[i][0].z); o[3]=(short)f2bf(ax[i][0].w);
      o[4]=(short)f2bf(ax[i][1].x); o[5]=(short)f2bf(ax[i][1].y);
      o[6]=(short)f2bf(ax[i][1].z); o[7]=(short)f2bf(ax[i][1].w);
      int r = r0 + 32*i; int idx = (r*BK + s8*8) ^ ((r&7)<<3);
      *(short8*)&As[buf][idx] = o; }};
  auto stageB_reg = [&](int buf){
    #pragma unroll
    for (int i=0;i<4;++i){
      short8 o;
      o[0]=(short)f2bf((float)bq[i][0].x*wsc[i]+wof[i]);
      o[1]=(short)f2bf((float)bq[i][0].y*wsc[i]+wof[i]);
      o[2]=(short)f2bf((float)bq[i][0].z*wsc[i]+wof[i]);
      o[3]=(short)f2bf((float)bq[i][0].w*wsc[i]+wof[i]);
      o[4]=(short)f2bf((float)bq[i][1].x*wsc[i]+wof[i]);
      o[5]=(short)f2bf((float)bq[i][1].y*wsc[i]+wof[i]);
      o[6]=(short)f2bf((float)bq[i][1].z*wsc[i]+wof[i]);
      o[7]=(short)f2bf((float)bq[i][1].w*wsc[i]+wof[i]);
      int r = r0 + 32*i; int idx = (r*BK + s8*8) ^ ((r&7)<<3);
      *(short8*)&Bs[buf][idx] = o; }};

  if constexpr (!PRE_A) loadA(0);
  if constexpr (!PRE_B) loadB(0);
  if constexpr (PRE_A) stageA_gll(0,0); else stageA_reg(0);
  if constexpr (PRE_B) stageB_gll(0,0); else stageB_reg(0);
  if constexpr (!PRE_A) { if (NT > 1) loadA(1); }
  if constexpr (!PRE_B) { if (NT > 1) loadB(1); }

  int cur = 0;
  for (int kt=0; kt<NT; ++kt){
    asm volatile("s_waitcnt vmcnt(0) lgkmcnt(0)" ::: "memory");
    __builtin_amdgcn_sched_barrier(0);
    __syncthreads();
    const int nxt = cur ^ 1;
    if (kt+1 < NT){
      if constexpr (PRE_A) stageA_gll(nxt, kt+1); else stageA_reg(nxt);
      if constexpr (PRE_B) stageB_gll(nxt, kt+1); else stageB_reg(nxt);
      if constexpr (!PRE_A) { if (kt+2 < NT) loadA(kt+2); }
      if constexpr (!PRE_B) { if (kt+2 < NT) loadB(kt+2); }
    }
    const ushort_t* as = As[cur];
    const ushort_t* bs = Bs[cur];
    #pragma unroll
    for (int kk=0; kk<2; ++kk){
      bf16x8 af[4], bfr[4];
      const int klo = kk*32 + ((lane>>4)<<3);
      #pragma unroll
      for (int mf=0; mf<4; ++mf){
        int r = wr*64 + mf*16 + (lane&15);
        af[mf] = *(const bf16x8*)&as[(r*BK + klo) ^ ((r&7)<<3)];
      }
      #pragma unroll
      for (int nf=0; nf<4; ++nf){
        int r = wc*64 + nf*16 + (lane&15);
        bfr[nf] = *(const bf16x8*)&bs[(r*BK + klo) ^ ((r&7)<<3)];
      }
      #pragma unroll
      for (int mf=0; mf<4; ++mf)
        #pragma unroll
        for (int nf=0; nf<4; ++nf)
          acc[mf][nf] = __builtin_amdgcn_mfma_f32_16x16x32_bf16(af[mf], bfr[nf], acc[mf][nf], 0,0,0);
    }
    cur = nxt;
  }
  const int cl = lane & 15, rq = (lane >> 4) << 2;
  #pragma unroll
  for (int nf=0; nf<4; ++nf){
    int col = bcol + wc*64 + nf*16 + cl;
    float bvs = g_bias[col];
    #pragma unroll
    for (int mf=0; mf<4; ++mf){
      int row = brow + wr*64 + mf*16 + rq;
      f32x4 v = acc[mf][nf];
      #pragma unroll
      for (int i=0;i<4;++i)
        Y[(size_t)(row+i)*N_DIM + col] = v[i] + bvs;
    }
  }
}

// ---------------- launch ----------------
extern "C" void kernel_launch(void* const* d_in, const int* in_sizes, int n_in,
                              void* d_out, int out_size, void* d_ws, size_t ws_size,
                              hipStream_t stream) {
  const float* x     = (const float*)d_in[0];
  const int*   qw    = (const int*)  d_in[1];
  const float* scale = (const float*)d_in[2];
  const float* zp    = (const float*)d_in[3];
  const float* bias  = (const float*)d_in[4];
  float* y = (float*)d_out;

  const size_t XB = (size_t)M_DIM*K_DIM*2;
  const size_t WB = (size_t)N_DIM*K_DIM*2;

  if (ws_size >= XB + WB){
    ushort_t* xb = (ushort_t*)d_ws;
    ushort_t* wb = (ushort_t*)((char*)d_ws + XB);
    cvt_x_kernel<<<2048, 256, 0, stream>>>(x, xb);
    cvt_w_kernel<<<2048, 256, 0, stream>>>(qw, scale, zp, wb);
    qgemm256<<<dim3((M_DIM/256)*(N_DIM/256)), dim3(512), 0, stream>>>(xb, wb, bias, y);
  } else if (ws_size >= WB){
    ushort_t* wb = (ushort_t*)d_ws;
    cvt_w_kernel<<<2048, 256, 0, stream>>>(qw, scale, zp, wb);
    qgemm<false,true><<<dim3((M_DIM/128)*(N_DIM/128)), dim3(256), 0, stream>>>(nullptr, x, wb, nullptr, scale, zp, bias, y);
  } else {
    qgemm<false,false><<<dim3((M_DIM/128)*(N_DIM/128)), dim3(256), 0, stream>>>(nullptr, x, nullptr, qw, scale, zp, bias, y);
  }
}